// Round 1
// baseline (122.948 us; speedup 1.0000x reference)
//
#include <hip/hip_runtime.h>
#include <hip/hip_bf16.h>

#define IW    4096
#define OW    4096
#define PC    64
#define BATCH 1024

__device__ __forceinline__ float sigmoidf_(float x) {
    return 1.0f / (1.0f + __expf(-x));
}

__device__ __forceinline__ unsigned short f2bfbits(float f) {
    union { __hip_bfloat16 h; unsigned short u; } cv;
    cv.h = __float2bfloat16(f);   // RNE
    return cv.u;
}

// K1: x [BATCH][IW] f32 -> xT [IW][BATCH] bf16 (tiled 64x64 transpose + cast)
__global__ __launch_bounds__(256) void k_transpose_cast(
        const float* __restrict__ x, unsigned short* __restrict__ xT) {
    __shared__ float tile[64][65];          // [c_local][b_local], +1 pad
    const int c0 = blockIdx.x * 64;         // input-width tile
    const int b0 = blockIdx.y * 64;         // batch tile
    const int t  = threadIdx.x;
    const int r  = t >> 4;                  // 0..15
    const int s  = t & 15;                  // 0..15
    #pragma unroll
    for (int it = 0; it < 4; ++it) {
        const int row = r + 16 * it;        // batch row in tile
        const float4 v = *reinterpret_cast<const float4*>(
            x + (size_t)(b0 + row) * IW + c0 + s * 4);
        tile[s * 4 + 0][row] = v.x;
        tile[s * 4 + 1][row] = v.y;
        tile[s * 4 + 2][row] = v.z;
        tile[s * 4 + 3][row] = v.w;
    }
    __syncthreads();
    #pragma unroll
    for (int it = 0; it < 4; ++it) {
        const int c = r + 16 * it;          // c_local
        ushort4 o;
        o.x = f2bfbits(tile[c][s * 4 + 0]);
        o.y = f2bfbits(tile[c][s * 4 + 1]);
        o.z = f2bfbits(tile[c][s * 4 + 2]);
        o.w = f2bfbits(tile[c][s * 4 + 3]);
        *reinterpret_cast<ushort4*>(xT + (size_t)(c0 + c) * BATCH + b0 + s * 4) = o;
    }
}

// K2: one block per output o; 256 threads, each owns 4 consecutive batches.
// Gather rows of xT (block-uniform row index -> coalesced 8B/lane loads).
__global__ __launch_bounds__(256) void k_gather(
        const unsigned short* __restrict__ xT,
        const int* __restrict__ sel,
        const float* __restrict__ w,
        const float* __restrict__ biases,
        unsigned short* __restrict__ outT) {
    __shared__ int   s_off[PC];
    __shared__ float s_wa[PC];
    const int o = blockIdx.x;
    const int t = threadIdx.x;
    if (t < PC) {
        s_off[t] = sel[o * PC + t] * (BATCH * 2);  // row byte offset
        s_wa[t]  = sigmoidf_(w[o * PC + t]);
    }
    __syncthreads();
    const char* base = (const char*)xT + (size_t)t * 8;  // 4 bf16 per thread
    float a0 = 0.f, a1 = 0.f, a2 = 0.f, a3 = 0.f;
    #pragma unroll 8
    for (int p = 0; p < PC; ++p) {
        const int   off = __builtin_amdgcn_readfirstlane(s_off[p]);
        const float wa  = s_wa[p];
        const uint2 raw = *reinterpret_cast<const uint2*>(base + off);
        const float v0 = __uint_as_float(raw.x << 16);
        const float v1 = __uint_as_float(raw.x & 0xffff0000u);
        const float v2 = __uint_as_float(raw.y << 16);
        const float v3 = __uint_as_float(raw.y & 0xffff0000u);
        a0 = fmaf(wa, v0, a0);
        a1 = fmaf(wa, v1, a1);
        a2 = fmaf(wa, v2, a2);
        a3 = fmaf(wa, v3, a3);
    }
    const float bo = biases[o];
    ushort4 ov;
    ov.x = f2bfbits(sigmoidf_(a0 - bo));
    ov.y = f2bfbits(sigmoidf_(a1 - bo));
    ov.z = f2bfbits(sigmoidf_(a2 - bo));
    ov.w = f2bfbits(sigmoidf_(a3 - bo));
    *reinterpret_cast<ushort4*>(outT + (size_t)o * BATCH + t * 4) = ov;
}

// K3: outT [OW][BATCH] bf16 -> out [BATCH][OW] f32 (tiled transpose + cast)
__global__ __launch_bounds__(256) void k_transpose_out(
        const unsigned short* __restrict__ outT, float* __restrict__ out) {
    __shared__ float tile[64][65];          // [o_local][b_local]
    const int o0 = blockIdx.x * 64;
    const int b0 = blockIdx.y * 64;
    const int t  = threadIdx.x;
    const int r  = t >> 4;
    const int s  = t & 15;
    #pragma unroll
    for (int it = 0; it < 4; ++it) {
        const int ol = r + 16 * it;
        const ushort4 v = *reinterpret_cast<const ushort4*>(
            outT + (size_t)(o0 + ol) * BATCH + b0 + s * 4);
        tile[ol][s * 4 + 0] = __uint_as_float((unsigned)v.x << 16);
        tile[ol][s * 4 + 1] = __uint_as_float((unsigned)v.y << 16);
        tile[ol][s * 4 + 2] = __uint_as_float((unsigned)v.z << 16);
        tile[ol][s * 4 + 3] = __uint_as_float((unsigned)v.w << 16);
    }
    __syncthreads();
    #pragma unroll
    for (int it = 0; it < 4; ++it) {
        const int bl = r + 16 * it;
        float4 v;
        v.x = tile[s * 4 + 0][bl];
        v.y = tile[s * 4 + 1][bl];
        v.z = tile[s * 4 + 2][bl];
        v.w = tile[s * 4 + 3][bl];
        *reinterpret_cast<float4*>(out + (size_t)(b0 + bl) * OW + o0 + s * 4) = v;
    }
}

// Fallback (correctness-only) if ws is too small for xT/outT staging.
__global__ __launch_bounds__(256) void k_naive(
        const float* __restrict__ x, const int* __restrict__ sel,
        const float* __restrict__ w, const float* __restrict__ biases,
        float* __restrict__ out) {
    __shared__ int   s_idx[PC];
    __shared__ float s_wa[PC];
    const int o = blockIdx.x;
    const int t = threadIdx.x;
    if (t < PC) {
        s_idx[t] = sel[o * PC + t];
        s_wa[t]  = sigmoidf_(w[o * PC + t]);
    }
    __syncthreads();
    const int b4 = t * 4;
    float a[4] = {0.f, 0.f, 0.f, 0.f};
    for (int p = 0; p < PC; ++p) {
        const int   idx = s_idx[p];
        const float wa  = s_wa[p];
        #pragma unroll
        for (int k = 0; k < 4; ++k)
            a[k] = fmaf(wa, x[(size_t)(b4 + k) * IW + idx], a[k]);
    }
    const float bo = biases[o];
    #pragma unroll
    for (int k = 0; k < 4; ++k)
        out[(size_t)(b4 + k) * OW + o] = sigmoidf_(a[k] - bo);
}

extern "C" void kernel_launch(void* const* d_in, const int* in_sizes, int n_in,
                              void* d_out, int out_size, void* d_ws, size_t ws_size,
                              hipStream_t stream) {
    const float* x      = (const float*)d_in[0];
    const int*   sel    = (const int*)d_in[1];
    const float* w      = (const float*)d_in[2];
    const float* biases = (const float*)d_in[3];
    float*       out    = (float*)d_out;

    const size_t xT_bytes   = (size_t)IW * BATCH * 2;   // 8 MB
    const size_t outT_bytes = (size_t)OW * BATCH * 2;   // 8 MB

    if (ws_size >= xT_bytes + outT_bytes) {
        unsigned short* xT   = (unsigned short*)d_ws;
        unsigned short* outT = (unsigned short*)((char*)d_ws + xT_bytes);
        k_transpose_cast<<<dim3(IW / 64, BATCH / 64), 256, 0, stream>>>(x, xT);
        k_gather<<<OW, 256, 0, stream>>>(xT, sel, w, biases, outT);
        k_transpose_out<<<dim3(OW / 64, BATCH / 64), 256, 0, stream>>>(outT, out);
    } else {
        k_naive<<<OW, 256, 0, stream>>>(x, sel, w, biases, out);
    }
}

// Round 2
// 112.883 us; speedup vs baseline: 1.0892x; 1.0892x over previous
//
#include <hip/hip_runtime.h>
#include <hip/hip_bf16.h>

#define IW    4096
#define OW    4096
#define PC    64
#define BATCH 1024
#define BQ    256          // batch-quarter: 4096 rows x 512B = 2MB, fits 4MB per-XCD L2

__device__ __forceinline__ float sigmoidf_(float x) {
    return 1.0f / (1.0f + __expf(-x));
}

__device__ __forceinline__ unsigned short f2bfbits(float f) {
    union { __hip_bfloat16 h; unsigned short u; } cv;
    cv.h = __float2bfloat16(f);   // RNE
    return cv.u;
}

// K1: x [BATCH][IW] f32 -> xT [IW][BATCH] bf16 (tiled 64x64 transpose + cast)
__global__ __launch_bounds__(256) void k_transpose_cast(
        const float* __restrict__ x, unsigned short* __restrict__ xT) {
    __shared__ float tile[64][65];          // [c_local][b_local], +1 pad
    const int c0 = blockIdx.x * 64;         // input-width tile
    const int b0 = blockIdx.y * 64;         // batch tile
    const int t  = threadIdx.x;
    const int r  = t >> 4;                  // 0..15
    const int s  = t & 15;                  // 0..15
    #pragma unroll
    for (int it = 0; it < 4; ++it) {
        const int row = r + 16 * it;        // batch row in tile
        const float4 v = *reinterpret_cast<const float4*>(
            x + (size_t)(b0 + row) * IW + c0 + s * 4);
        tile[s * 4 + 0][row] = v.x;
        tile[s * 4 + 1][row] = v.y;
        tile[s * 4 + 2][row] = v.z;
        tile[s * 4 + 3][row] = v.w;
    }
    __syncthreads();
    #pragma unroll
    for (int it = 0; it < 4; ++it) {
        const int c = r + 16 * it;          // c_local
        ushort4 o;
        o.x = f2bfbits(tile[c][s * 4 + 0]);
        o.y = f2bfbits(tile[c][s * 4 + 1]);
        o.z = f2bfbits(tile[c][s * 4 + 2]);
        o.w = f2bfbits(tile[c][s * 4 + 3]);
        *reinterpret_cast<ushort4*>(xT + (size_t)(c0 + c) * BATCH + b0 + s * 4) = o;
    }
}

// K2: grid (OW/4, BATCH/BQ); 4 waves/block, one output per wave.
// Wave reads row-quarters of xT: 64 lanes x uint2(8B) = 512B = one quarter-row.
// Quarter (blockIdx.y) is the slow grid dim -> per-phase working set is 2MB,
// L2-resident on every XCD.
__global__ __launch_bounds__(256) void k_gather(
        const unsigned short* __restrict__ xT,
        const int* __restrict__ sel,
        const float* __restrict__ wts,
        const float* __restrict__ biases,
        unsigned short* __restrict__ outT) {
    __shared__ int   s_off[4][PC];
    __shared__ float s_wa[4][PC];
    const int t    = threadIdx.x;
    const int wv   = t >> 6;                 // wave id 0..3
    const int lane = t & 63;
    const int o    = blockIdx.x * 4 + wv;
    // PC == 64 == wave width: each wave loads its own output's params
    s_off[wv][lane] = sel[o * PC + lane] * (BATCH * 2);   // row byte offset
    s_wa[wv][lane]  = sigmoidf_(wts[o * PC + lane]);
    __syncthreads();
    const int bq = blockIdx.y * BQ;          // batch-quarter base
    const char* base = (const char*)xT + (size_t)bq * 2 + (size_t)lane * 8;
    float a0 = 0.f, a1 = 0.f, a2 = 0.f, a3 = 0.f;
    #pragma unroll 8
    for (int p = 0; p < PC; ++p) {
        const int   off = __builtin_amdgcn_readfirstlane(s_off[wv][p]);
        const float wa  = s_wa[wv][p];
        const uint2 raw = *reinterpret_cast<const uint2*>(base + off);
        const float v0 = __uint_as_float(raw.x << 16);
        const float v1 = __uint_as_float(raw.x & 0xffff0000u);
        const float v2 = __uint_as_float(raw.y << 16);
        const float v3 = __uint_as_float(raw.y & 0xffff0000u);
        a0 = fmaf(wa, v0, a0);
        a1 = fmaf(wa, v1, a1);
        a2 = fmaf(wa, v2, a2);
        a3 = fmaf(wa, v3, a3);
    }
    const float bo = biases[o];
    ushort4 ov;
    ov.x = f2bfbits(sigmoidf_(a0 - bo));
    ov.y = f2bfbits(sigmoidf_(a1 - bo));
    ov.z = f2bfbits(sigmoidf_(a2 - bo));
    ov.w = f2bfbits(sigmoidf_(a3 - bo));
    *reinterpret_cast<ushort4*>(outT + (size_t)o * BATCH + bq + lane * 4) = ov;
}

// K3: outT [OW][BATCH] bf16 -> out [BATCH][OW] f32 (tiled transpose + cast)
__global__ __launch_bounds__(256) void k_transpose_out(
        const unsigned short* __restrict__ outT, float* __restrict__ out) {
    __shared__ float tile[64][65];          // [o_local][b_local]
    const int o0 = blockIdx.x * 64;
    const int b0 = blockIdx.y * 64;
    const int t  = threadIdx.x;
    const int r  = t >> 4;
    const int s  = t & 15;
    #pragma unroll
    for (int it = 0; it < 4; ++it) {
        const int ol = r + 16 * it;
        const ushort4 v = *reinterpret_cast<const ushort4*>(
            outT + (size_t)(o0 + ol) * BATCH + b0 + s * 4);
        tile[ol][s * 4 + 0] = __uint_as_float((unsigned)v.x << 16);
        tile[ol][s * 4 + 1] = __uint_as_float((unsigned)v.y << 16);
        tile[ol][s * 4 + 2] = __uint_as_float((unsigned)v.z << 16);
        tile[ol][s * 4 + 3] = __uint_as_float((unsigned)v.w << 16);
    }
    __syncthreads();
    #pragma unroll
    for (int it = 0; it < 4; ++it) {
        const int bl = r + 16 * it;
        float4 v;
        v.x = tile[s * 4 + 0][bl];
        v.y = tile[s * 4 + 1][bl];
        v.z = tile[s * 4 + 2][bl];
        v.w = tile[s * 4 + 3][bl];
        *reinterpret_cast<float4*>(out + (size_t)(b0 + bl) * OW + o0 + s * 4) = v;
    }
}

// Fallback (correctness-only) if ws is too small for xT/outT staging.
__global__ __launch_bounds__(256) void k_naive(
        const float* __restrict__ x, const int* __restrict__ sel,
        const float* __restrict__ w, const float* __restrict__ biases,
        float* __restrict__ out) {
    __shared__ int   s_idx[PC];
    __shared__ float s_wa[PC];
    const int o = blockIdx.x;
    const int t = threadIdx.x;
    if (t < PC) {
        s_idx[t] = sel[o * PC + t];
        s_wa[t]  = sigmoidf_(w[o * PC + t]);
    }
    __syncthreads();
    const int b4 = t * 4;
    float a[4] = {0.f, 0.f, 0.f, 0.f};
    for (int p = 0; p < PC; ++p) {
        const int   idx = s_idx[p];
        const float wa  = s_wa[p];
        #pragma unroll
        for (int k = 0; k < 4; ++k)
            a[k] = fmaf(wa, x[(size_t)(b4 + k) * IW + idx], a[k]);
    }
    const float bo = biases[o];
    #pragma unroll
    for (int k = 0; k < 4; ++k)
        out[(size_t)(b4 + k) * OW + o] = sigmoidf_(a[k] - bo);
}

extern "C" void kernel_launch(void* const* d_in, const int* in_sizes, int n_in,
                              void* d_out, int out_size, void* d_ws, size_t ws_size,
                              hipStream_t stream) {
    const float* x      = (const float*)d_in[0];
    const int*   sel    = (const int*)d_in[1];
    const float* w      = (const float*)d_in[2];
    const float* biases = (const float*)d_in[3];
    float*       out    = (float*)d_out;

    const size_t xT_bytes   = (size_t)IW * BATCH * 2;   // 8 MB
    const size_t outT_bytes = (size_t)OW * BATCH * 2;   // 8 MB

    if (ws_size >= xT_bytes + outT_bytes) {
        unsigned short* xT   = (unsigned short*)d_ws;
        unsigned short* outT = (unsigned short*)((char*)d_ws + xT_bytes);
        k_transpose_cast<<<dim3(IW / 64, BATCH / 64), 256, 0, stream>>>(x, xT);
        k_gather<<<dim3(OW / 4, BATCH / BQ), 256, 0, stream>>>(xT, sel, w, biases, outT);
        k_transpose_out<<<dim3(OW / 64, BATCH / 64), 256, 0, stream>>>(outT, out);
    } else {
        k_naive<<<OW, 256, 0, stream>>>(x, sel, w, biases, out);
    }
}

// Round 3
// 112.724 us; speedup vs baseline: 1.0907x; 1.0014x over previous
//
#include <hip/hip_runtime.h>
#include <hip/hip_bf16.h>

#define IW    4096
#define OW    4096
#define PC    64
#define BATCH 1024
#define BQ    256          // batch-quarter: 4096 rows x 512B = 2MB, fits 4MB per-XCD L2
#define NXCD  8

__device__ __forceinline__ float sigmoidf_(float x) {
    return 1.0f / (1.0f + __expf(-x));
}

__device__ __forceinline__ unsigned short f2bfbits(float f) {
    union { __hip_bfloat16 h; unsigned short u; } cv;
    cv.h = __float2bfloat16(f);   // RNE
    return cv.u;
}

// K1: x [BATCH][IW] f32 -> xT [IW][BATCH] bf16 (tiled 64x64 transpose + cast)
__global__ __launch_bounds__(256) void k_transpose_cast(
        const float* __restrict__ x, unsigned short* __restrict__ xT) {
    __shared__ float tile[64][65];          // [c_local][b_local], +1 pad
    const int c0 = blockIdx.x * 64;         // input-width tile
    const int b0 = blockIdx.y * 64;         // batch tile
    const int t  = threadIdx.x;
    const int r  = t >> 4;                  // 0..15
    const int s  = t & 15;                  // 0..15
    #pragma unroll
    for (int it = 0; it < 4; ++it) {
        const int row = r + 16 * it;        // batch row in tile
        const float4 v = *reinterpret_cast<const float4*>(
            x + (size_t)(b0 + row) * IW + c0 + s * 4);
        tile[s * 4 + 0][row] = v.x;
        tile[s * 4 + 1][row] = v.y;
        tile[s * 4 + 2][row] = v.z;
        tile[s * 4 + 3][row] = v.w;
    }
    __syncthreads();
    #pragma unroll
    for (int it = 0; it < 4; ++it) {
        const int c = r + 16 * it;          // c_local
        ushort4 o;
        o.x = f2bfbits(tile[c][s * 4 + 0]);
        o.y = f2bfbits(tile[c][s * 4 + 1]);
        o.z = f2bfbits(tile[c][s * 4 + 2]);
        o.w = f2bfbits(tile[c][s * 4 + 3]);
        *reinterpret_cast<ushort4*>(xT + (size_t)(c0 + c) * BATCH + b0 + s * 4) = o;
    }
}

// K2: flat grid of 4096 blocks; XCD-affine quarter assignment.
// blockIdx round-robins across the 8 XCDs, so quarter = (bid&7)&3 pins each
// XCD's L2 to ONE 2MB batch-quarter of xT for the whole kernel (both dispatch
// phases). For fixed quarter q, blocks with bid&7 in {q, q+4} enumerate
// rank 0..1023 exactly once -> each (output, quarter) computed once.
// 4 waves/block, one output per wave; 64 lanes x uint2(8B) = 512B = one
// quarter-row of xT per load instruction.
__global__ __launch_bounds__(256) void k_gather(
        const unsigned short* __restrict__ xT,
        const int* __restrict__ sel,
        const float* __restrict__ wts,
        const float* __restrict__ biases,
        unsigned short* __restrict__ outT) {
    __shared__ int   s_off[4][PC];
    __shared__ float s_wa[4][PC];
    const int bid  = blockIdx.x;
    const int xcd  = bid & 7;
    const int q    = xcd & 3;                       // this XCD's quarter
    const int rank = ((bid >> 3) << 1) + (xcd >> 2); // 0..1023
    const int t    = threadIdx.x;
    const int wv   = t >> 6;                 // wave id 0..3
    const int lane = t & 63;
    const int o    = rank * 4 + wv;
    // PC == 64 == wave width: each wave loads its own output's params
    s_off[wv][lane] = sel[o * PC + lane] * (BATCH * 2);   // row byte offset
    s_wa[wv][lane]  = sigmoidf_(wts[o * PC + lane]);
    __syncthreads();
    const int bq = q * BQ;                   // batch-quarter base
    const char* base = (const char*)xT + (size_t)bq * 2 + (size_t)lane * 8;
    float a0 = 0.f, a1 = 0.f, a2 = 0.f, a3 = 0.f;
    #pragma unroll 8
    for (int p = 0; p < PC; ++p) {
        const int   off = __builtin_amdgcn_readfirstlane(s_off[wv][p]);
        const float wa  = s_wa[wv][p];
        const uint2 raw = *reinterpret_cast<const uint2*>(base + off);
        const float v0 = __uint_as_float(raw.x << 16);
        const float v1 = __uint_as_float(raw.x & 0xffff0000u);
        const float v2 = __uint_as_float(raw.y << 16);
        const float v3 = __uint_as_float(raw.y & 0xffff0000u);
        a0 = fmaf(wa, v0, a0);
        a1 = fmaf(wa, v1, a1);
        a2 = fmaf(wa, v2, a2);
        a3 = fmaf(wa, v3, a3);
    }
    const float bo = biases[o];
    ushort4 ov;
    ov.x = f2bfbits(sigmoidf_(a0 - bo));
    ov.y = f2bfbits(sigmoidf_(a1 - bo));
    ov.z = f2bfbits(sigmoidf_(a2 - bo));
    ov.w = f2bfbits(sigmoidf_(a3 - bo));
    *reinterpret_cast<ushort4*>(outT + (size_t)o * BATCH + bq + lane * 4) = ov;
}

// K3: outT [OW][BATCH] bf16 -> out [BATCH][OW] f32 (tiled transpose + cast)
__global__ __launch_bounds__(256) void k_transpose_out(
        const unsigned short* __restrict__ outT, float* __restrict__ out) {
    __shared__ float tile[64][65];          // [o_local][b_local]
    const int o0 = blockIdx.x * 64;
    const int b0 = blockIdx.y * 64;
    const int t  = threadIdx.x;
    const int r  = t >> 4;
    const int s  = t & 15;
    #pragma unroll
    for (int it = 0; it < 4; ++it) {
        const int ol = r + 16 * it;
        const ushort4 v = *reinterpret_cast<const ushort4*>(
            outT + (size_t)(o0 + ol) * BATCH + b0 + s * 4);
        tile[ol][s * 4 + 0] = __uint_as_float((unsigned)v.x << 16);
        tile[ol][s * 4 + 1] = __uint_as_float((unsigned)v.y << 16);
        tile[ol][s * 4 + 2] = __uint_as_float((unsigned)v.z << 16);
        tile[ol][s * 4 + 3] = __uint_as_float((unsigned)v.w << 16);
    }
    __syncthreads();
    #pragma unroll
    for (int it = 0; it < 4; ++it) {
        const int bl = r + 16 * it;
        float4 v;
        v.x = tile[s * 4 + 0][bl];
        v.y = tile[s * 4 + 1][bl];
        v.z = tile[s * 4 + 2][bl];
        v.w = tile[s * 4 + 3][bl];
        *reinterpret_cast<float4*>(out + (size_t)(b0 + bl) * OW + o0 + s * 4) = v;
    }
}

// Fallback (correctness-only) if ws is too small for xT/outT staging.
__global__ __launch_bounds__(256) void k_naive(
        const float* __restrict__ x, const int* __restrict__ sel,
        const float* __restrict__ w, const float* __restrict__ biases,
        float* __restrict__ out) {
    __shared__ int   s_idx[PC];
    __shared__ float s_wa[PC];
    const int o = blockIdx.x;
    const int t = threadIdx.x;
    if (t < PC) {
        s_idx[t] = sel[o * PC + t];
        s_wa[t]  = sigmoidf_(w[o * PC + t]);
    }
    __syncthreads();
    const int b4 = t * 4;
    float a[4] = {0.f, 0.f, 0.f, 0.f};
    for (int p = 0; p < PC; ++p) {
        const int   idx = s_idx[p];
        const float wa  = s_wa[p];
        #pragma unroll
        for (int k = 0; k < 4; ++k)
            a[k] = fmaf(wa, x[(size_t)(b4 + k) * IW + idx], a[k]);
    }
    const float bo = biases[o];
    #pragma unroll
    for (int k = 0; k < 4; ++k)
        out[(size_t)(b4 + k) * OW + o] = sigmoidf_(a[k] - bo);
}

extern "C" void kernel_launch(void* const* d_in, const int* in_sizes, int n_in,
                              void* d_out, int out_size, void* d_ws, size_t ws_size,
                              hipStream_t stream) {
    const float* x      = (const float*)d_in[0];
    const int*   sel    = (const int*)d_in[1];
    const float* w      = (const float*)d_in[2];
    const float* biases = (const float*)d_in[3];
    float*       out    = (float*)d_out;

    const size_t xT_bytes   = (size_t)IW * BATCH * 2;   // 8 MB
    const size_t outT_bytes = (size_t)OW * BATCH * 2;   // 8 MB

    if (ws_size >= xT_bytes + outT_bytes) {
        unsigned short* xT   = (unsigned short*)d_ws;
        unsigned short* outT = (unsigned short*)((char*)d_ws + xT_bytes);
        k_transpose_cast<<<dim3(IW / 64, BATCH / 64), 256, 0, stream>>>(x, xT);
        k_gather<<<dim3((OW / 4) * (BATCH / BQ)), 256, 0, stream>>>(xT, sel, w, biases, outT);
        k_transpose_out<<<dim3(OW / 64, BATCH / 64), 256, 0, stream>>>(outT, out);
    } else {
        k_naive<<<OW, 256, 0, stream>>>(x, sel, w, biases, out);
    }
}